// Round 6
// baseline (387.659 us; speedup 1.0000x reference)
//
#include <hip/hip_runtime.h>
#include <cfloat>

#define GT 16
#define NCLS 81
#define TPB 256
#define MAXP 8732
#define TROWS 64
#define WF4 324              // float4 per wave slice: 16 rows * 81 / 4
#define TF4 (TROWS*NCLS/4)   // 1296 float4 per tile

__device__ __forceinline__ float smoothl1(float d){
  float a = fabsf(d);
  return a < 1.0f ? 0.5f*a*a : a - 0.5f;
}

// Kernel 1: fused per-batch assignment (one block per batch, all state in
// LDS — no cross-block reductions). Phase 1: per-prior IoU max over GT +
// per-GT best prior. Phase 2: best-prior override (last g wins), labels
// (uchar), encode + smooth-L1 over positives. Fuses accumulator init.
__global__ __launch_bounds__(TPB) void assign_kernel(
    const float* __restrict__ priors,     // (P,4) xywh
    const float* __restrict__ gt_boxes,   // (B,GT,4) xyxy
    const int*   __restrict__ gt_labels,  // (B,GT)
    const float* __restrict__ box_reg,    // (B,P,4)
    unsigned char* __restrict__ labels_out, // (B,P)
    float* __restrict__ sl1_sum,          // (B)
    int*   __restrict__ num_pos,          // (B)
    float* __restrict__ ce_pos,           // (B)
    float* __restrict__ out,              // (2)
    int P)
{
  const int b = blockIdx.x;
  const int tid = threadIdx.x, wave = tid >> 6, lane = tid & 63;

  __shared__ float s_mv[MAXP];
  __shared__ unsigned char s_match[MAXP];
  __shared__ float gx0[GT], gy0[GT], gx1[GT], gy1[GT], ga[GT];
  __shared__ int glab[GT], bp[GT];
  __shared__ float redv[4*GT]; __shared__ int redi[4*GT];
  __shared__ float rs[4]; __shared__ int rc[4];

  if (tid == 0) ce_pos[b] = 0.0f;
  if (b == 0 && tid < 2) out[tid] = 0.0f;
  if (tid < GT){
    const float4 gb = ((const float4*)gt_boxes)[b*GT + tid];
    gx0[tid]=gb.x; gy0[tid]=gb.y; gx1[tid]=gb.z; gy1[tid]=gb.w;
    ga[tid] = (gb.z-gb.x)*(gb.w-gb.y);
    glab[tid] = gt_labels[b*GT + tid];
  }
  __syncthreads();

  float bv[GT]; int bi[GT];
  #pragma unroll
  for (int g=0; g<GT; ++g){ bv[g] = -1.0f; bi[g] = 0x7fffffff; }
  for (int p = tid; p < P; p += TPB){
    const float4 pr = ((const float4*)priors)[p];
    const float px0 = pr.x - pr.z*0.5f, py0 = pr.y - pr.w*0.5f;
    const float px1 = pr.x + pr.z*0.5f, py1 = pr.y + pr.w*0.5f;
    const float pa = (px1-px0)*(py1-py0);
    float mv = -1.0f; int mi = 0;
    #pragma unroll
    for (int g=0; g<GT; ++g){
      const float w = fmaxf(fminf(gx1[g],px1) - fmaxf(gx0[g],px0), 0.0f);
      const float h = fmaxf(fminf(gy1[g],py1) - fmaxf(gy0[g],py0), 0.0f);
      const float inter = w*h;
      const float iou = inter / (ga[g] + pa - inter);
      if (iou > mv){ mv = iou; mi = g; }              // first-max over g
      if (iou > bv[g]){ bv[g] = iou; bi[g] = p; }     // first-max over p
    }
    s_mv[p] = mv;
    s_match[p] = (unsigned char)mi;
  }
  #pragma unroll
  for (int g=0; g<GT; ++g){
    float v = bv[g]; int i = bi[g];
    for (int off=32; off>0; off>>=1){
      const float ov = __shfl_down(v, off);
      const int   oi = __shfl_down(i, off);
      if (ov > v || (ov == v && oi < i)){ v = ov; i = oi; }
    }
    if (lane == 0){ redv[wave*GT+g] = v; redi[wave*GT+g] = i; }
  }
  __syncthreads();
  if (tid < GT){
    float v = redv[tid]; int i = redi[tid];
    for (int w=1; w<4; ++w){
      const float ov = redv[w*GT+tid]; const int oi = redi[w*GT+tid];
      if (ov > v || (ov == v && oi < i)){ v = ov; i = oi; }
    }
    bp[tid] = i;
  }
  __syncthreads();

  float sl1 = 0.0f; int cnt = 0;
  for (int p = tid; p < P; p += TPB){
    float mv = s_mv[p];
    int g = s_match[p];
    #pragma unroll
    for (int g2=0; g2<GT; ++g2) if (bp[g2] == p){ mv = 2.0f; g = g2; }  // last g wins
    int lab = 0;
    if (mv >= 0.5f){
      lab = glab[g]; cnt++;
      const float4 pr = ((const float4*)priors)[p];
      const float ctrx = (gx0[g]+gx1[g])*0.5f, ctry = (gy0[g]+gy1[g])*0.5f;
      const float wx = gx1[g]-gx0[g], wy = gy1[g]-gy0[g];
      const float tx = (ctrx - pr.x) / (0.1f*pr.z);
      const float ty = (ctry - pr.y) / (0.1f*pr.w);
      const float tw = __logf(wx/pr.z) / 0.2f;
      const float th = __logf(wy/pr.w) / 0.2f;
      const float4 br = ((const float4*)box_reg)[(long long)b*P + p];
      sl1 += smoothl1(br.x - tx) + smoothl1(br.y - ty)
           + smoothl1(br.z - tw) + smoothl1(br.w - th);
    }
    labels_out[(long long)b*P + p] = (unsigned char)lab;
  }
  float v = sl1; int c = cnt;
  for (int off=32; off>0; off>>=1){ v += __shfl_down(v, off); c += __shfl_down(c, off); }
  if (lane == 0){ rs[wave] = v; rc[wave] = c; }
  __syncthreads();
  if (tid == 0){
    sl1_sum[b] = rs[0]+rs[1]+rs[2]+rs[3];
    num_pos[b] = rc[0]+rc[1]+rc[2]+rc[3];
  }
}

// Kernel 2: barrier-free pipelined LSE. Wave-private 16-row LDS slices, no
// __syncthreads; prefetch next slice into registers during compute. Class
// loop is stride-4 interleaved (c = q, q+4, ...) -> compile-time 20-iter
// unroll (batched ds_reads, <=2-way bank alias = free) + 1-elem tail (q==0).
__global__ __launch_bounds__(TPB) void lse_pipe(
    const float* __restrict__ logits,        // (B*P, 81)
    const unsigned char* __restrict__ labels,// (B*P)
    float* __restrict__ bg,                  // (B*P)
    float* __restrict__ ce_pos,              // (B)
    int P, int NT)                           // NT = B*P/TROWS = 8732 exact
{
  __shared__ float s[TROWS*NCLS];       // 4 waves * 324 float4 = 20736 B
  const int tid = threadIdx.x;
  const int wave = tid >> 6, lane = tid & 63;
  const int rl = lane >> 2, q = lane & 3;
  const int G = gridDim.x;
  int t = blockIdx.x;
  if (t >= NT) return;

  float4 r0,r1,r2,r3,r4,r5; int labc = 0;
  {
    const float4* src = (const float4*)logits + (long long)t*TF4 + wave*WF4;
    r0 = src[lane]; r1 = src[lane+64]; r2 = src[lane+128];
    r3 = src[lane+192]; r4 = src[lane+256];
    if (lane < 4) r5 = src[lane+320];
    if (q == 0) labc = labels[t*TROWS + wave*16 + rl];
  }
  float4* sd = (float4*)(s) + wave*WF4;
  const float* x = s + wave*(WF4*4) + rl*NCLS;
  for (; t < NT; t += G){
    sd[lane] = r0; sd[lane+64] = r1; sd[lane+128] = r2;
    sd[lane+192] = r3; sd[lane+256] = r4;
    if (lane < 4) sd[lane+320] = r5;
    const int lab = labc;
    const int tn = t + G;
    if (tn < NT){                       // prefetch next slice (stays in flight)
      const float4* src = (const float4*)logits + (long long)tn*TF4 + wave*WF4;
      r0 = src[lane]; r1 = src[lane+64]; r2 = src[lane+128];
      r3 = src[lane+192]; r4 = src[lane+256];
      if (lane < 4) r5 = src[lane+320];
      if (q == 0) labc = labels[tn*TROWS + wave*16 + rl];
    }
    float sum = 0.0f;
    #pragma unroll
    for (int i = 0; i < 20; ++i) sum += __expf(x[q + 4*i]);
    float x0 = 0.0f;
    if (q == 0){ x0 = x[0]; sum += __expf(x[80]); }
    sum += __shfl_xor(sum, 1);
    sum += __shfl_xor(sum, 2);
    if (q == 0){
      const int row = t*TROWS + wave*16 + rl;
      const float lse = __logf(sum);
      float bgv;
      if (lab > 0){
        const int b = row / P;
        const float xl = x[lab];        // LDS gather, no vm wait
        atomicAdd(&ce_pos[b], lse - xl);
        bgv = 0.0f;
      } else {
        bgv = fmaxf(lse - x0, 0.0f);    // clamp: radix needs >=0
      }
      bg[row] = bgv;
    }
  }
}

// Kernel 3: per-batch top-(3*num_pos) sum. Count-only 8-bit radix select
// (16 replicated histograms, stride 257 -> replicas in different banks),
// then one pass summing values strictly above threshold; ties contribute
// krem * threshold. Fused final /N reduce into out[2].
__global__ __launch_bounds__(TPB) void topk_kernel(
    const float* __restrict__ bg,
    const int*   __restrict__ num_pos,
    const float* __restrict__ sl1_sum,
    const float* __restrict__ ce_pos,
    float* __restrict__ out,
    int P, int B)
{
  const int b = blockIdx.x;
  const int tid = threadIdx.x;
  const int wave = tid >> 6, lane = tid & 63;
  const int rep = tid & 15;
  __shared__ float sv[MAXP];
  __shared__ unsigned cntR[16][257];
  __shared__ unsigned s_wc[4];
  __shared__ float    s_wf[4];
  __shared__ unsigned s_prefix;
  __shared__ int s_krem, s_chosen, s_newk;

  {
    const float4* srcp = (const float4*)(bg + (long long)b * P);
    float4* dst = (float4*)sv;
    for (int j = tid; j < P/4; j += TPB) dst[j] = srcp[j];
  }
  if (tid == 0){
    const int k = 3*num_pos[b];
    s_krem = k < P ? k : P-1;
    s_prefix = 0u;
  }
  __syncthreads();

  for (int level=0; level<4; ++level){
    const int shift = 24 - 8*level;
    for (int i = tid; i < 16*257; i += TPB) ((unsigned*)cntR)[i] = 0u;
    __syncthreads();
    const unsigned pref = s_prefix;
    const int k = s_krem;
    for (int j = tid; j < P/4; j += TPB){
      const float4 f4 = ((const float4*)sv)[j];
      #pragma unroll
      for (int e=0; e<4; ++e){
        const unsigned key = __float_as_uint((&f4.x)[e]);
        const bool ok = (level == 0) || ((key >> (shift+8)) == pref);
        if (ok) atomicAdd(&cntR[rep][(key >> shift) & 255u], 1u);
      }
    }
    __syncthreads();
    const int rb = 255 - tid;
    unsigned c = 0;
    #pragma unroll
    for (int r=0; r<16; ++r) c += cntR[r][rb];
    unsigned cv = c;
    #pragma unroll
    for (int off=1; off<64; off<<=1){
      const unsigned oc = __shfl_up(cv, off);
      if (lane >= off) cv += oc;
    }
    if (lane == 63) s_wc[wave] = cv;
    __syncthreads();
    unsigned addc = 0;
    for (int w=0; w<4; ++w) if (w < wave) addc += s_wc[w];
    const unsigned S = cv - c + addc;   // count in bins > rb (matching prefix)
    if ((int)S <= k && k < (int)(S + c)){
      s_chosen = rb; s_newk = k - (int)S;      // exactly one thread
    }
    __syncthreads();
    if (tid == 0){
      s_krem = s_newk;
      s_prefix = (pref << 8) | (unsigned)s_chosen;
    }
    __syncthreads();
  }
  const unsigned T = s_prefix;
  float acc = 0.0f;
  for (int j = tid; j < P/4; j += TPB){
    const float4 f4 = ((const float4*)sv)[j];
    #pragma unroll
    for (int e=0; e<4; ++e){
      const float f = (&f4.x)[e];
      if (__float_as_uint(f) > T) acc += f;
    }
  }
  for (int off=32; off>0; off>>=1) acc += __shfl_down(acc, off);
  if (lane == 0) s_wf[wave] = acc;
  __syncthreads();
  if (tid < 64){                        // wave 0: N = sum(num_pos), /N shares
    float n = 0.0f;
    for (int i = tid; i < B; i += 64) n += (float)num_pos[i];
    for (int off=32; off>0; off>>=1) n += __shfl_down(n, off);
    if (tid == 0){
      const float N = n;
      const float cls = s_wf[0]+s_wf[1]+s_wf[2]+s_wf[3]
                      + (float)s_krem * __uint_as_float(T);
      atomicAdd(&out[0], sl1_sum[b] / N);
      atomicAdd(&out[1], (ce_pos[b] + cls) / N);
    }
  }
}

extern "C" void kernel_launch(void* const* d_in, const int* in_sizes, int n_in,
                              void* d_out, int out_size, void* d_ws, size_t ws_size,
                              hipStream_t stream) {
  const float* priors = (const float*)d_in[0];
  const float* logits = (const float*)d_in[1];
  const float* boxreg = (const float*)d_in[2];
  const float* gtb    = (const float*)d_in[3];
  const int*   gtl    = (const int*)d_in[4];
  const int P = in_sizes[0] / 4;          // 8732
  const int B = in_sizes[4] / GT;         // 64
  const long long BP = (long long)B * P;

  char* ws = (char*)d_ws;
  unsigned char* labels = (unsigned char*)ws;       // BP bytes
  float* bg     = (float*)(ws + BP);                // BP float
  char* tail = ws + BP*5;
  float* sl1_s  = (float*)(tail);
  int*   npos   = (int*)  (tail + 256);
  float* ce_pos = (float*)(tail + 512);

  assign_kernel<<<B, TPB, 0, stream>>>(priors, gtb, gtl, boxreg,
                                       labels, sl1_s, npos, ce_pos,
                                       (float*)d_out, P);
  const int NT = (int)(BP / TROWS);       // 8732 exact
  const int G = 1792;                     // 7 blocks/CU (20.7 KB LDS)
  lse_pipe<<<G, TPB, 0, stream>>>(logits, labels, bg, ce_pos, P, NT);
  topk_kernel<<<B, TPB, 0, stream>>>(bg, npos, sl1_s, ce_pos, (float*)d_out, P, B);
}